// Round 3
// baseline (9405.145 us; speedup 1.0000x reference)
//
#include <hip/hip_runtime.h>
#include <stdint.h>

#define NUSER 200000
#define NREPO 100000
#define NEDGE 1500000

typedef unsigned short u16;
typedef unsigned int u32;

// Workspace layout (bytes) — total 166,800,000
#define WS_ABUF_U 0UL
#define WS_ABUF_R 102400000UL
#define WS_CU     153600000UL
#define WS_CR     154400000UL
#define WS_EU     154800000UL
#define WS_ER     160800000UL
#define WS_NEEDED 166800000UL

__device__ __forceinline__ float bflo(u32 p) { return __uint_as_float(p << 16); }
__device__ __forceinline__ float bfhi(u32 p) { return __uint_as_float(p & 0xffff0000u); }
__device__ __forceinline__ u16 f2bf(float f) {
    u32 u = __float_as_uint(f);
    u32 r = (u + 0x7fffu + ((u >> 16) & 1u)) >> 16;
    return (u16)r;
}

__global__ void sentinel_kernel(float* out) { out[threadIdx.x] = 1234.5f; }

__global__ void zero_f32_kernel(float4* __restrict__ p, long n4) {
    long i = (long)blockIdx.x * blockDim.x + threadIdx.x;
    long s = (long)gridDim.x * blockDim.x;
    float4 z = make_float4(0.f, 0.f, 0.f, 0.f);
    for (; i < n4; i += s) p[i] = z;
}

// Decode edge_stars into canonical int32 eu/er whether the harness stored it
// as int64 or int32. int64 layout <=> odd u32 words (hi words of nonneg
// indices) of the first 2048 words are ALL zero; random int32 indices can't
// produce 1024 consecutive zero odd-words. Flag derived per-block (L2-hot).
__global__ void convert_edges_kernel(const u32* __restrict__ e,
                                     int* __restrict__ eu, int* __restrict__ er) {
    __shared__ int any_odd;
    int t = threadIdx.x;
    if (t == 0) any_odd = 0;
    __syncthreads();
    u32 acc = 0;
#pragma unroll
    for (int r = 0; r < 4; ++r) acc |= e[2 * (256 * r + t) + 1];
    if (acc != 0) any_odd = 1;   // benign race: all writers store 1
    __syncthreads();
    int is64 = !any_odd;
    int i = blockIdx.x * blockDim.x + t;
    if (i < NEDGE) {
        if (is64) {
            eu[i] = (int)e[2 * i];
            er[i] = (int)e[2 * (NEDGE + i)];
        } else {
            eu[i] = (int)e[i];
            er[i] = (int)e[NEDGE + i];
        }
    }
}

__global__ void count_kernel(const int* __restrict__ eu, const int* __restrict__ er,
                             float* __restrict__ cu, float* __restrict__ cr) {
    int i = blockIdx.x * blockDim.x + threadIdx.x;
    if (i < NEDGE) {
        unsafeAtomicAdd(&cu[eu[i]], 1.0f);
        unsafeAtomicAdd(&cr[er[i]], 1.0f);
    }
}

// One wave per edge: 64 lanes x float2 -> 128 fp32 atomic adds into A[d].
__global__ void scatter_kernel(const float2* __restrict__ feat,
                               const int* __restrict__ sidx, const int* __restrict__ didx,
                               float* __restrict__ A) {
    int t = blockIdx.x * blockDim.x + threadIdx.x;
    int e = t >> 6;       // grid sized exactly: e < NEDGE always
    int lane = t & 63;
    int s = sidx[e];
    int d = didx[e];
    float2 w = feat[s * 64 + lane];       // 512B per wave, coalesced
    float* dst = A + d * 128 + lane * 2;
    unsafeAtomicAdd(dst, w.x);
    unsafeAtomicAdd(dst + 1, w.y);
}

// out[n,o] = (A[n,:]/max(cnt,1)) @ Wl[:,o] + bias[o] + xdst[n,:] @ Wr[:,o], opt relu.
// 256 threads = 2 node-slots x 128 output channels; 64 nodes per block.
// Weight columns cached per-thread as packed bf16x2 (128 VGPRs); mean/x fp32.
// Safe when out == xdst (in-place): rows staged into LDS behind a barrier
// before any write, and blocks own disjoint rows.
__global__ __launch_bounds__(256, 2)
void transform_kernel(const float* __restrict__ A, const float* __restrict__ cnt,
                      const float* __restrict__ xdst,
                      const float* __restrict__ Wl, const float* __restrict__ bias,
                      const float* __restrict__ Wr,
                      float* __restrict__ out, int N, int do_relu) {
    __shared__ __align__(16) float sM[2][128];
    __shared__ __align__(16) float sX[2][128];

    int tid = threadIdx.x;
    int o = tid & 127;
    int half = tid >> 7;

    u32 wl2[64], wr2[64];
#pragma unroll
    for (int kk = 0; kk < 64; ++kk) {
        float a = Wl[(2 * kk) * 128 + o];
        float b = Wl[(2 * kk + 1) * 128 + o];
        wl2[kk] = (u32)f2bf(a) | ((u32)f2bf(b) << 16);
        float c = Wr[(2 * kk) * 128 + o];
        float d = Wr[(2 * kk + 1) * 128 + o];
        wr2[kk] = (u32)f2bf(c) | ((u32)f2bf(d) << 16);
    }
    float biasv = bias[o];
    int base = blockIdx.x * 64;

    for (int nn = 0; nn < 64; nn += 2) {
        int node = base + nn + half;
        bool valid = node < N;
        __syncthreads();
        if (valid) {
            float c = cnt[node];
            float inv = 1.0f / fmaxf(c, 1.0f);
            sM[half][o] = A[node * 128 + o] * inv;
            sX[half][o] = xdst[node * 128 + o];
        }
        __syncthreads();
        if (valid) {
            const float4* M4 = (const float4*)sM[half];   // 32 entries
            const float4* X4 = (const float4*)sX[half];
            float acc = biasv;
#pragma unroll
            for (int j = 0; j < 16; ++j) {
                float4 ma = M4[2 * j];
                float4 mb = M4[2 * j + 1];
                float4 xa = X4[2 * j];
                float4 xb = X4[2 * j + 1];
                u32 w0 = wl2[4 * j], w1 = wl2[4 * j + 1], w2 = wl2[4 * j + 2], w3 = wl2[4 * j + 3];
                acc += ma.x * bflo(w0) + ma.y * bfhi(w0);
                acc += ma.z * bflo(w1) + ma.w * bfhi(w1);
                acc += mb.x * bflo(w2) + mb.y * bfhi(w2);
                acc += mb.z * bflo(w3) + mb.w * bfhi(w3);
                u32 v0 = wr2[4 * j], v1 = wr2[4 * j + 1], v2 = wr2[4 * j + 2], v3 = wr2[4 * j + 3];
                acc += xa.x * bflo(v0) + xa.y * bfhi(v0);
                acc += xa.z * bflo(v1) + xa.w * bfhi(v1);
                acc += xb.x * bflo(v2) + xb.y * bfhi(v2);
                acc += xb.z * bflo(v3) + xb.w * bfhi(v3);
            }
            if (do_relu) acc = fmaxf(acc, 0.0f);
            out[node * 128 + o] = acc;
        }
    }
}

extern "C" void kernel_launch(void* const* d_in, const int* in_sizes, int n_in,
                              void* d_out, int out_size, void* d_ws, size_t ws_size,
                              hipStream_t stream) {
    const float* x_user = (const float*)d_in[0];
    const float* x_repo = (const float*)d_in[1];
    const u32* edges_raw = (const u32*)d_in[2];
    const float* Wl1s = (const float*)d_in[3], *bl1s = (const float*)d_in[4], *Wr1s = (const float*)d_in[5];
    const float* Wl1r = (const float*)d_in[6], *bl1r = (const float*)d_in[7], *Wr1r = (const float*)d_in[8];
    const float* Wl2s = (const float*)d_in[9], *bl2s = (const float*)d_in[10], *Wr2s = (const float*)d_in[11];
    const float* Wl2r = (const float*)d_in[12], *bl2r = (const float*)d_in[13], *Wr2r = (const float*)d_in[14];

    float* out_user = (float*)d_out;                          // also hosts user_h
    float* out_repo = (float*)d_out + (size_t)NUSER * 128;    // also hosts repo_h

    if (ws_size < WS_NEEDED) {   // diagnosable failure: absmax ~1232
        hipLaunchKernelGGL(sentinel_kernel, dim3(1), dim3(256), 0, stream, out_user);
        return;
    }

    char* ws = (char*)d_ws;
    float* Abuf_u = (float*)(ws + WS_ABUF_U);   // NUSER*128 f32
    float* Abuf_r = (float*)(ws + WS_ABUF_R);   // NREPO*128 f32
    float* cu     = (float*)(ws + WS_CU);
    float* cr     = (float*)(ws + WS_CR);
    int* eu       = (int*)(ws + WS_EU);
    int* er       = (int*)(ws + WS_ER);

    // canonical int32 edge arrays
    hipLaunchKernelGGL(convert_edges_kernel, dim3((NEDGE + 255) / 256), dim3(256), 0, stream,
                       edges_raw, eu, er);

    // degree counts (cu,cr contiguous: one zero pass of 300000 floats)
    hipLaunchKernelGGL(zero_f32_kernel, dim3(512), dim3(256), 0, stream, (float4*)cu, (long)(300000 / 4));
    hipLaunchKernelGGL(count_kernel, dim3((NEDGE + 255) / 256), dim3(256), 0, stream, eu, er, cu, cr);

    // Layer 1, stars: mean over x_user per repo; repo_h (in d_out repo region)
    hipLaunchKernelGGL(zero_f32_kernel, dim3(2048), dim3(256), 0, stream, (float4*)Abuf_r, (long)(NREPO * 128 / 4));
    hipLaunchKernelGGL(scatter_kernel, dim3(NEDGE / 4), dim3(256), 0, stream, (const float2*)x_user, eu, er, Abuf_r);
    hipLaunchKernelGGL(transform_kernel, dim3((NREPO + 63) / 64), dim3(256), 0, stream,
                       Abuf_r, cr, x_repo, Wl1s, bl1s, Wr1s, out_repo, NREPO, 1);

    // Layer 1, rev_stars: mean over x_repo per user; user_h (in d_out user region)
    hipLaunchKernelGGL(zero_f32_kernel, dim3(2048), dim3(256), 0, stream, (float4*)Abuf_u, (long)(NUSER * 128 / 4));
    hipLaunchKernelGGL(scatter_kernel, dim3(NEDGE / 4), dim3(256), 0, stream, (const float2*)x_repo, er, eu, Abuf_u);
    hipLaunchKernelGGL(transform_kernel, dim3((NUSER + 63) / 64), dim3(256), 0, stream,
                       Abuf_u, cu, x_user, Wl1r, bl1r, Wr1r, out_user, NUSER, 1);

    // Layer 2: BOTH scatters first (hiddens still intact), then in-place transforms.
    hipLaunchKernelGGL(zero_f32_kernel, dim3(2048), dim3(256), 0, stream, (float4*)Abuf_r, (long)(NREPO * 128 / 4));
    hipLaunchKernelGGL(scatter_kernel, dim3(NEDGE / 4), dim3(256), 0, stream, (const float2*)out_user, eu, er, Abuf_r);
    hipLaunchKernelGGL(zero_f32_kernel, dim3(2048), dim3(256), 0, stream, (float4*)Abuf_u, (long)(NUSER * 128 / 4));
    hipLaunchKernelGGL(scatter_kernel, dim3(NEDGE / 4), dim3(256), 0, stream, (const float2*)out_repo, er, eu, Abuf_u);

    hipLaunchKernelGGL(transform_kernel, dim3((NREPO + 63) / 64), dim3(256), 0, stream,
                       Abuf_r, cr, out_repo, Wl2s, bl2s, Wr2s, out_repo, NREPO, 0);
    hipLaunchKernelGGL(transform_kernel, dim3((NUSER + 63) / 64), dim3(256), 0, stream,
                       Abuf_u, cu, out_user, Wl2r, bl2r, Wr2r, out_user, NUSER, 0);
}

// Round 4
// 1106.836 us; speedup vs baseline: 8.4973x; 8.4973x over previous
//
#include <hip/hip_runtime.h>
#include <stdint.h>

#define NUSER 200000
#define NREPO 100000
#define NEDGE 1500000

typedef unsigned short u16;
typedef unsigned int u32;
typedef __bf16 bf16x8 __attribute__((ext_vector_type(8)));
typedef float f32x4 __attribute__((ext_vector_type(4)));

// ---- workspace layout (bytes) ----
#define OFF_B0   0UL            // 51,200,000  mean_u -> hu (bf16 200000x128)
#define OFF_B1   51200000UL     // 25,600,000  mean_r -> hr
#define OFF_B2   76800000UL     // 51,200,000  xu_bf ; later mean_u2
#define OFF_B3   128000000UL    // 25,600,000  xr_bf ; later mean_r2
#define OFF_COLR 153600000UL    //  6,000,000  CSR col (user ids) by repo
#define OFF_COLU 159600000UL    //  6,000,000  CSR col (repo ids) by user
#define OFF_POSR 165600000UL    //    400,000
#define OFF_POSU 166000000UL    //    800,000
#define OFF_PART 166800000UL    //      4,096
#define OFF_WT   166804096UL    //    262,144  4 x [128n][256k] bf16
#define WS_NEEDED 167066240UL

__device__ __forceinline__ float bflo(u32 p) { return __uint_as_float(p << 16); }
__device__ __forceinline__ float bfhi(u32 p) { return __uint_as_float(p & 0xffff0000u); }
__device__ __forceinline__ u16 f2bf(float f) {
    u32 u = __float_as_uint(f);
    return (u16)((u + 0x7fffu + ((u >> 16) & 1u)) >> 16);
}
__device__ __forceinline__ bf16x8 as_bf16x8(uint4 u) {
    union { uint4 a; bf16x8 b; } x; x.a = u; return x.b;
}

__global__ void sentinel_kernel(float* out) { out[threadIdx.x] = 1234.5f; }

__global__ void zero_i32_kernel(int4* __restrict__ p, int n4) {
    int i = blockIdx.x * blockDim.x + threadIdx.x;
    if (i < n4) p[i] = make_int4(0, 0, 0, 0);
}

// fp32 -> bf16 (packed), 4 elems/thread; n multiple of 4
__global__ void cvt_bf16_kernel(const float4* __restrict__ in, uint2* __restrict__ out, int n4) {
    int i = blockIdx.x * blockDim.x + threadIdx.x;
    if (i < n4) {
        float4 v = in[i];
        uint2 o;
        o.x = (u32)f2bf(v.x) | ((u32)f2bf(v.y) << 16);
        o.y = (u32)f2bf(v.z) | ((u32)f2bf(v.w) << 16);
        out[i] = o;
    }
}

// Wt[n*256 + k] = bf16( k<128 ? Wl[k][n] : Wr[k-128][n] );  grid 128 x 256
__global__ void wprep_kernel(const float* __restrict__ Wl, const float* __restrict__ Wr,
                             u16* __restrict__ Wt) {
    int idx = blockIdx.x * blockDim.x + threadIdx.x;   // 0..32767
    int n = idx >> 8, k = idx & 255;
    float v = (k < 128) ? Wl[k * 128 + n] : Wr[(k - 128) * 128 + n];
    Wt[idx] = f2bf(v);
}

// int64/int32-robust edge decode, per-block flag (first 2048 words, L2-hot)
__device__ __forceinline__ bool detect_is64(const u32* e) {
    __shared__ int any_odd;
    int t = threadIdx.x;
    if (t == 0) any_odd = 0;
    __syncthreads();
    u32 acc = 0;
#pragma unroll
    for (int r = 0; r < 4; ++r) acc |= e[2 * (256 * r + t) + 1];
    if (acc != 0) any_odd = 1;
    __syncthreads();
    return !any_odd;
}

__global__ void hist_kernel(const u32* __restrict__ e, int* __restrict__ pos_u, int* __restrict__ pos_r) {
    bool is64 = detect_is64(e);
    int i = blockIdx.x * blockDim.x + threadIdx.x;
    if (i < NEDGE) {
        int u = is64 ? (int)e[2 * i] : (int)e[i];
        int r = is64 ? (int)e[2 * (NEDGE + i)] : (int)e[NEDGE + i];
        atomicAdd(&pos_u[u], 1);
        atomicAdd(&pos_r[r], 1);
    }
}

__global__ void fill_kernel(const u32* __restrict__ e, int* __restrict__ pos_u, int* __restrict__ pos_r,
                            int* __restrict__ col_u, int* __restrict__ col_r) {
    bool is64 = detect_is64(e);
    int i = blockIdx.x * blockDim.x + threadIdx.x;
    if (i < NEDGE) {
        int u = is64 ? (int)e[2 * i] : (int)e[i];
        int r = is64 ? (int)e[2 * (NEDGE + i)] : (int)e[NEDGE + i];
        int iu = atomicAdd(&pos_u[u], 1);
        col_u[iu] = r;
        int ir = atomicAdd(&pos_r[r], 1);
        col_r[ir] = u;
    }
}

// ---- 3-kernel exclusive scan (in-place on a[], partials in part[]) ----
__global__ void scan_partial(const int* __restrict__ a, int n, int* __restrict__ part) {
    __shared__ int red[256];
    int t = threadIdx.x, b = blockIdx.x;
    int base = b * 1024 + t * 4, s = 0;
#pragma unroll
    for (int j = 0; j < 4; ++j) { int i = base + j; if (i < n) s += a[i]; }
    red[t] = s; __syncthreads();
    for (int off = 128; off > 0; off >>= 1) { if (t < off) red[t] += red[t + off]; __syncthreads(); }
    if (t == 0) part[b] = red[0];
}
__global__ void scan_top(int* __restrict__ part, int nb) {
    __shared__ int s0[256], s1[256];
    int t = threadIdx.x;
    s0[t] = (t < nb) ? part[t] : 0;
    __syncthreads();
    int* src = s0; int* dst = s1;
    for (int off = 1; off < 256; off <<= 1) {
        int x = src[t]; if (t >= off) x += src[t - off];
        dst[t] = x; __syncthreads();
        int* tmp = src; src = dst; dst = tmp;
    }
    if (t < nb) part[t] = (t == 0) ? 0 : src[t - 1];
}
__global__ void scan_apply(int* __restrict__ a, int n, const int* __restrict__ part) {
    __shared__ int s0[256], s1[256];
    int t = threadIdx.x, b = blockIdx.x;
    int base = b * 1024 + t * 4;
    int v[4]; int s = 0;
#pragma unroll
    for (int j = 0; j < 4; ++j) { int i = base + j; v[j] = (i < n) ? a[i] : 0; s += v[j]; }
    s0[t] = s; __syncthreads();
    int* src = s0; int* dst = s1;
    for (int off = 1; off < 256; off <<= 1) {
        int x = src[t]; if (t >= off) x += src[t - off];
        dst[t] = x; __syncthreads();
        int* tmp = src; src = dst; dst = tmp;
    }
    int run = part[b] + ((t == 0) ? 0 : src[t - 1]);
#pragma unroll
    for (int j = 0; j < 4; ++j) { int i = base + j; if (i < n) { a[i] = run; run += v[j]; } }
}

// One wave per destination: mean of bf16 source rows (fp32 accum), write bf16.
// pos[] holds bucket ENDS (post-fill); start = pos[d-1] (or 0).
__global__ void gather_mean_kernel(const u16* __restrict__ feat, const int* __restrict__ col,
                                   const int* __restrict__ pos, u16* __restrict__ outm, int ndst) {
    int gw = (blockIdx.x * blockDim.x + threadIdx.x) >> 6;
    int lane = threadIdx.x & 63;
    if (gw >= ndst) return;
    int start = (gw == 0) ? 0 : pos[gw - 1];
    int end = pos[gw];
    float ax = 0.f, ay = 0.f;
    int e = start;
    for (; e + 3 < end; e += 4) {
        int s0 = col[e], s1 = col[e + 1], s2 = col[e + 2], s3 = col[e + 3];
        u32 w0 = *(const u32*)(feat + (size_t)s0 * 128 + lane * 2);
        u32 w1 = *(const u32*)(feat + (size_t)s1 * 128 + lane * 2);
        u32 w2 = *(const u32*)(feat + (size_t)s2 * 128 + lane * 2);
        u32 w3 = *(const u32*)(feat + (size_t)s3 * 128 + lane * 2);
        ax += bflo(w0) + bflo(w1) + bflo(w2) + bflo(w3);
        ay += bfhi(w0) + bfhi(w1) + bfhi(w2) + bfhi(w3);
    }
    for (; e < end; ++e) {
        int s0 = col[e];
        u32 w0 = *(const u32*)(feat + (size_t)s0 * 128 + lane * 2);
        ax += bflo(w0); ay += bfhi(w0);
    }
    float inv = 1.0f / fmaxf((float)(end - start), 1.0f);
    u32 o = (u32)f2bf(ax * inv) | ((u32)f2bf(ay * inv) << 16);
    *(u32*)(outm + (size_t)gw * 128 + lane * 2) = o;
}

// MFMA transform: out[N x 128] = [mean|x] @ [Wl;Wr] + bias (opt relu).
// Block: 4 waves, M-tile 64; wave w owns cols [32w,32w+32). Safe in-place
// (out_bf == A): each block reads/writes only its own 64 rows, staged first.
__global__ __launch_bounds__(256)
void transform_mfma(const u16* __restrict__ A, const u16* __restrict__ X,
                    const u16* __restrict__ Wt, const float* __restrict__ bias,
                    u16* __restrict__ out_bf, float* __restrict__ out_f32,
                    int N, int do_relu) {
    __shared__ __align__(16) u16 sA[64][264];   // 256 k + 8 pad (2-way bank = free)
    int tid = threadIdx.x;
    int w = tid >> 6, lane = tid & 63;
    int q = lane >> 4, n = lane & 15;
    int nb = w * 32;

    // B-fragments: Wt[n][k] = W[k][n], bf16; one dwordx4 each, held in VGPRs.
    bf16x8 bfrag[2][8];
#pragma unroll
    for (int nt = 0; nt < 2; ++nt)
#pragma unroll
        for (int ks = 0; ks < 8; ++ks)
            bfrag[nt][ks] = as_bf16x8(*(const uint4*)(Wt + (size_t)(nb + nt * 16 + n) * 256 + ks * 32 + q * 8));
    float bv[2] = { bias[nb + n], bias[nb + 16 + n] };

    int base = blockIdx.x * 64;
    // stage A-tile: thread -> row r = tid>>2, chunk c = tid&3 (64B from A, 64B from X)
    {
        int r = tid >> 2, c = tid & 3;
        int node = base + r;
        uint4 z = make_uint4(0, 0, 0, 0);
        uint4 va[4], vx[4];
        if (node < N) {
            const uint4* pa = (const uint4*)(A + (size_t)node * 128 + c * 32);
            const uint4* px = (const uint4*)(X + (size_t)node * 128 + c * 32);
#pragma unroll
            for (int j = 0; j < 4; ++j) { va[j] = pa[j]; vx[j] = px[j]; }
        } else {
#pragma unroll
            for (int j = 0; j < 4; ++j) { va[j] = z; vx[j] = z; }
        }
#pragma unroll
        for (int j = 0; j < 4; ++j) {
            *(uint4*)&sA[r][c * 32 + j * 8] = va[j];
            *(uint4*)&sA[r][128 + c * 32 + j * 8] = vx[j];
        }
    }
    __syncthreads();

    f32x4 zz = { 0.f, 0.f, 0.f, 0.f };
    f32x4 acc[4][2];
#pragma unroll
    for (int mt = 0; mt < 4; ++mt) { acc[mt][0] = zz; acc[mt][1] = zz; }

#pragma unroll
    for (int ks = 0; ks < 8; ++ks)
#pragma unroll
        for (int mt = 0; mt < 4; ++mt) {
            bf16x8 af = *(const bf16x8*)&sA[mt * 16 + n][ks * 32 + q * 8];
            acc[mt][0] = __builtin_amdgcn_mfma_f32_16x16x32_bf16(af, bfrag[0][ks], acc[mt][0], 0, 0, 0);
            acc[mt][1] = __builtin_amdgcn_mfma_f32_16x16x32_bf16(af, bfrag[1][ks], acc[mt][1], 0, 0, 0);
        }

    // C/D: row = q*4 + reg, col = lane&15 (verified m89/m91)
#pragma unroll
    for (int mt = 0; mt < 4; ++mt) {
        int row0 = base + mt * 16 + q * 4;
#pragma unroll
        for (int nt = 0; nt < 2; ++nt) {
            int colg = nb + nt * 16 + n;
#pragma unroll
            for (int r = 0; r < 4; ++r) {
                int row = row0 + r;
                if (row < N) {
                    float v = acc[mt][nt][r] + bv[nt];
                    if (do_relu) v = fmaxf(v, 0.f);
                    if (out_bf) out_bf[(size_t)row * 128 + colg] = f2bf(v);
                    else        out_f32[(size_t)row * 128 + colg] = v;
                }
            }
        }
    }
}

extern "C" void kernel_launch(void* const* d_in, const int* in_sizes, int n_in,
                              void* d_out, int out_size, void* d_ws, size_t ws_size,
                              hipStream_t stream) {
    const float* x_user = (const float*)d_in[0];
    const float* x_repo = (const float*)d_in[1];
    const u32* edges = (const u32*)d_in[2];
    const float* Wl1s = (const float*)d_in[3], *bl1s = (const float*)d_in[4], *Wr1s = (const float*)d_in[5];
    const float* Wl1r = (const float*)d_in[6], *bl1r = (const float*)d_in[7], *Wr1r = (const float*)d_in[8];
    const float* Wl2s = (const float*)d_in[9], *bl2s = (const float*)d_in[10], *Wr2s = (const float*)d_in[11];
    const float* Wl2r = (const float*)d_in[12], *bl2r = (const float*)d_in[13], *Wr2r = (const float*)d_in[14];

    float* out_user = (float*)d_out;
    float* out_repo = (float*)d_out + (size_t)NUSER * 128;

    if (ws_size < WS_NEEDED) {
        hipLaunchKernelGGL(sentinel_kernel, dim3(1), dim3(256), 0, stream, out_user);
        return;
    }

    char* ws = (char*)d_ws;
    u16* B0 = (u16*)(ws + OFF_B0);
    u16* B1 = (u16*)(ws + OFF_B1);
    u16* B2 = (u16*)(ws + OFF_B2);
    u16* B3 = (u16*)(ws + OFF_B3);
    int* col_r = (int*)(ws + OFF_COLR);
    int* col_u = (int*)(ws + OFF_COLU);
    int* pos_r = (int*)(ws + OFF_POSR);
    int* pos_u = (int*)(ws + OFF_POSU);
    int* part  = (int*)(ws + OFF_PART);
    u16* wt1s = (u16*)(ws + OFF_WT);
    u16* wt1r = wt1s + 32768;
    u16* wt2s = wt1r + 32768;
    u16* wt2r = wt2s + 32768;

    // input converts + weight prep
    hipLaunchKernelGGL(cvt_bf16_kernel, dim3(25000), dim3(256), 0, stream,
                       (const float4*)x_user, (uint2*)B2, NUSER * 128 / 4);
    hipLaunchKernelGGL(cvt_bf16_kernel, dim3(12500), dim3(256), 0, stream,
                       (const float4*)x_repo, (uint2*)B3, NREPO * 128 / 4);
    hipLaunchKernelGGL(wprep_kernel, dim3(128), dim3(256), 0, stream, Wl1s, Wr1s, wt1s);
    hipLaunchKernelGGL(wprep_kernel, dim3(128), dim3(256), 0, stream, Wl1r, Wr1r, wt1r);
    hipLaunchKernelGGL(wprep_kernel, dim3(128), dim3(256), 0, stream, Wl2s, Wr2s, wt2s);
    hipLaunchKernelGGL(wprep_kernel, dim3(128), dim3(256), 0, stream, Wl2r, Wr2r, wt2r);

    // CSR build: zero counts -> hist -> scan(r) -> scan(u) -> fill (pos -> bucket ends)
    hipLaunchKernelGGL(zero_i32_kernel, dim3(294), dim3(256), 0, stream, (int4*)pos_r, 300000 / 4);
    hipLaunchKernelGGL(hist_kernel, dim3(5860), dim3(256), 0, stream, edges, pos_u, pos_r);
    hipLaunchKernelGGL(scan_partial, dim3(98), dim3(256), 0, stream, pos_r, NREPO, part);
    hipLaunchKernelGGL(scan_top, dim3(1), dim3(256), 0, stream, part, 98);
    hipLaunchKernelGGL(scan_apply, dim3(98), dim3(256), 0, stream, pos_r, NREPO, part);
    hipLaunchKernelGGL(scan_partial, dim3(196), dim3(256), 0, stream, pos_u, NUSER, part);
    hipLaunchKernelGGL(scan_top, dim3(1), dim3(256), 0, stream, part, 196);
    hipLaunchKernelGGL(scan_apply, dim3(196), dim3(256), 0, stream, pos_u, NUSER, part);
    hipLaunchKernelGGL(fill_kernel, dim3(5860), dim3(256), 0, stream, edges, pos_u, pos_r, col_u, col_r);

    // Layer 1: gathers then transforms (in-place mean -> hidden, relu)
    hipLaunchKernelGGL(gather_mean_kernel, dim3(25000), dim3(256), 0, stream, B2, col_r, pos_r, B1, NREPO);
    hipLaunchKernelGGL(gather_mean_kernel, dim3(50000), dim3(256), 0, stream, B3, col_u, pos_u, B0, NUSER);
    hipLaunchKernelGGL(transform_mfma, dim3((NREPO + 63) / 64), dim3(256), 0, stream,
                       B1, B3, wt1s, bl1s, B1, (float*)nullptr, NREPO, 1);
    hipLaunchKernelGGL(transform_mfma, dim3((NUSER + 63) / 64), dim3(256), 0, stream,
                       B0, B2, wt1r, bl1r, B0, (float*)nullptr, NUSER, 1);

    // Layer 2: gathers over hiddens, transforms write fp32 d_out
    hipLaunchKernelGGL(gather_mean_kernel, dim3(25000), dim3(256), 0, stream, B0, col_r, pos_r, B3, NREPO);
    hipLaunchKernelGGL(gather_mean_kernel, dim3(50000), dim3(256), 0, stream, B1, col_u, pos_u, B2, NUSER);
    hipLaunchKernelGGL(transform_mfma, dim3((NREPO + 63) / 64), dim3(256), 0, stream,
                       B3, B1, wt2s, bl2s, (u16*)nullptr, out_repo, NREPO, 0);
    hipLaunchKernelGGL(transform_mfma, dim3((NUSER + 63) / 64), dim3(256), 0, stream,
                       B2, B0, wt2r, bl2r, (u16*)nullptr, out_user, NUSER, 0);
}

// Round 5
// 800.699 us; speedup vs baseline: 11.7462x; 1.3823x over previous
//
#include <hip/hip_runtime.h>
#include <stdint.h>

#define NUSER 200000
#define NREPO 100000
#define NEDGE 1500000

#define RB 98        // repo buckets (dst>>10)
#define UB 196       // user buckets (dst>>10)
#define RCAP 17500   // per-bucket record capacity (mean 15360, +17 sigma)
#define UCAP 9000    // per-bucket record capacity (mean 7680, +15 sigma)

typedef unsigned short u16;
typedef unsigned int u32;
typedef __bf16 bf16x8 __attribute__((ext_vector_type(8)));
typedef float f32x4 __attribute__((ext_vector_type(4)));

// ---- workspace layout (bytes) ----
// records overlay the B0 region: dead before cvt_bf16 writes B2/B3 and
// before gathers write B0/B1 (launch order guarantees this).
#define OFF_RECR 0UL            //  6,860,000  u32[98*17500]
#define OFF_RECU 6860000UL      //  7,056,000  u32[196*9000]
#define OFF_B0   0UL            // 51,200,000  mean_u -> hu (bf16 200000x128)
#define OFF_B1   51200000UL     // 25,600,000  mean_r -> hr
#define OFF_B2   76800000UL     // 51,200,000  xu_bf ; later mean_u2
#define OFF_B3   128000000UL    // 25,600,000  xr_bf ; later mean_r2
#define OFF_COLR 153600000UL    //  6,000,000
#define OFF_COLU 159600000UL    //  6,000,000
#define OFF_POSR 165600000UL    //    400,000
#define OFF_POSU 166000000UL    //    800,000
#define OFF_WT   166800000UL    //    262,144  4 x [128n][256k] bf16
#define OFF_CUR  167062144UL    //  gcur_r(400) gcur_u(800) cb_r(400) cb_u(800)
#define WS_NEEDED 167064544UL

__device__ __forceinline__ float bflo(u32 p) { return __uint_as_float(p << 16); }
__device__ __forceinline__ float bfhi(u32 p) { return __uint_as_float(p & 0xffff0000u); }
__device__ __forceinline__ u16 f2bf(float f) {
    u32 u = __float_as_uint(f);
    return (u16)((u + 0x7fffu + ((u >> 16) & 1u)) >> 16);
}
__device__ __forceinline__ bf16x8 as_bf16x8(uint4 u) {
    union { uint4 a; bf16x8 b; } x; x.a = u; return x.b;
}

__global__ void sentinel_kernel(float* out) { out[threadIdx.x] = 1234.5f; }

__global__ void zero_i32_kernel(int4* __restrict__ p, int n4) {
    int i = blockIdx.x * blockDim.x + threadIdx.x;
    if (i < n4) p[i] = make_int4(0, 0, 0, 0);
}

// fp32 -> bf16 (packed), 4 elems/thread
__global__ void cvt_bf16_kernel(const float4* __restrict__ in, uint2* __restrict__ out, int n4) {
    int i = blockIdx.x * blockDim.x + threadIdx.x;
    if (i < n4) {
        float4 v = in[i];
        uint2 o;
        o.x = (u32)f2bf(v.x) | ((u32)f2bf(v.y) << 16);
        o.y = (u32)f2bf(v.z) | ((u32)f2bf(v.w) << 16);
        out[i] = o;
    }
}

// Wt[n*256 + k] = bf16( k<128 ? Wl[k][n] : Wr[k-128][n] )
__global__ void wprep_kernel(const float* __restrict__ Wl, const float* __restrict__ Wr,
                             u16* __restrict__ Wt) {
    int idx = blockIdx.x * blockDim.x + threadIdx.x;
    int n = idx >> 8, k = idx & 255;
    float v = (k < 128) ? Wl[k * 128 + n] : Wr[(k - 128) * 128 + n];
    Wt[idx] = f2bf(v);
}

// int64/int32-robust edge decode flag (first 2048 words, L2-hot)
__device__ __forceinline__ bool detect_is64(const u32* e) {
    __shared__ int any_odd;
    int t = threadIdx.x;
    if (t == 0) any_odd = 0;
    __syncthreads();
    u32 acc = 0;
#pragma unroll
    for (int r = 0; r < 4; ++r) acc |= e[2 * (256 * r + t) + 1];
    if (acc != 0) any_odd = 1;
    __syncthreads();
    return !any_odd;
}

// Pass A: bin edges by dst>>10 into per-bucket record regions (both
// directions in one pass). Per-block LDS histogram -> one global atomicAdd
// per (block,bucket) -> dense runs of packed records (src<<10 | dst&1023).
__global__ __launch_bounds__(256)
void passA_bin(const u32* __restrict__ e, u32* __restrict__ rec_r, u32* __restrict__ rec_u,
               int* __restrict__ gcur_r, int* __restrict__ gcur_u) {
    __shared__ int cntR[RB], cntU[UB], baseR[RB], baseU[UB];
    bool is64 = detect_is64(e);
    int t = threadIdx.x;
    for (int i = t; i < RB; i += 256) cntR[i] = 0;
    for (int i = t; i < UB; i += 256) cntU[i] = 0;
    __syncthreads();
    int base = blockIdx.x * 4096;
    int us[16], rs[16];
#pragma unroll
    for (int j = 0; j < 16; ++j) {
        int i = base + j * 256 + t;
        int u = -1, r = -1;
        if (i < NEDGE) {
            u = is64 ? (int)e[2 * i] : (int)e[i];
            r = is64 ? (int)e[2 * (NEDGE + i)] : (int)e[NEDGE + i];
        }
        us[j] = u; rs[j] = r;
        if (u >= 0) { atomicAdd(&cntR[r >> 10], 1); atomicAdd(&cntU[u >> 10], 1); }
    }
    __syncthreads();
    for (int i = t; i < RB; i += 256) baseR[i] = cntR[i] ? atomicAdd(&gcur_r[i], cntR[i]) : 0;
    for (int i = t; i < UB; i += 256) baseU[i] = cntU[i] ? atomicAdd(&gcur_u[i], cntU[i]) : 0;
    __syncthreads();
    for (int i = t; i < RB; i += 256) cntR[i] = 0;
    for (int i = t; i < UB; i += 256) cntU[i] = 0;
    __syncthreads();
#pragma unroll
    for (int j = 0; j < 16; ++j) {
        int u = us[j], r = rs[j];
        if (u >= 0) {
            int br = r >> 10, bu = u >> 10;
            int rk = baseR[br] + atomicAdd(&cntR[br], 1);
            if (rk < RCAP) rec_r[br * RCAP + rk] = ((u32)u << 10) | (u32)(r & 1023);
            int ku = baseU[bu] + atomicAdd(&cntU[bu], 1);
            if (ku < UCAP) rec_u[bu * UCAP + ku] = ((u32)r << 10) | (u32)(u & 1023);
        }
    }
}

// exclusive scan of bucket sizes -> dense col base per bucket (one block)
__global__ void bucket_scan(const int* __restrict__ gcur_r, const int* __restrict__ gcur_u,
                            int* __restrict__ cb_r, int* __restrict__ cb_u) {
    __shared__ int s0[256], s1[256];
    int t = threadIdx.x;
    // repo
    s0[t] = (t < RB) ? min(gcur_r[t], RCAP) : 0;
    __syncthreads();
    int* src = s0; int* dst = s1;
    for (int off = 1; off < 256; off <<= 1) {
        int x = src[t]; if (t >= off) x += src[t - off];
        dst[t] = x; __syncthreads();
        int* tmp = src; src = dst; dst = tmp;
    }
    if (t < RB) cb_r[t] = (t == 0) ? 0 : src[t - 1];
    __syncthreads();
    // user
    src[t] = 0; __syncthreads();   // normalize: reuse s-arrays
    s0[t] = (t < UB) ? min(gcur_u[t], UCAP) : 0;
    __syncthreads();
    src = s0; dst = s1;
    for (int off = 1; off < 256; off <<= 1) {
        int x = src[t]; if (t >= off) x += src[t - off];
        dst[t] = x; __syncthreads();
        int* tmp = src; src = dst; dst = tmp;
    }
    if (t < UB) cb_u[t] = (t == 0) ? 0 : src[t - 1];
}

// Pass B: one block per bucket. Count local dsts in LDS, block-scan, write
// pos (inclusive ends, global col coords) sequentially, then scatter col —
// random writes confined to a ~60KB L2-resident window (~1x amplification).
__global__ __launch_bounds__(256)
void passB_build(const u32* __restrict__ rec_r, const u32* __restrict__ rec_u,
                 const int* __restrict__ gcur_r, const int* __restrict__ gcur_u,
                 const int* __restrict__ cb_r, const int* __restrict__ cb_u,
                 int* __restrict__ col_r, int* __restrict__ col_u,
                 int* __restrict__ pos_r, int* __restrict__ pos_u) {
    __shared__ int cnt[1024];
    __shared__ int excl[1024];
    __shared__ int sc0[256], sc1[256];
    int b = blockIdx.x;
    const u32* rec; int count, colbase, dstbase, ndst; int* col; int* pos;
    if (b < RB) {
        rec = rec_r + (size_t)b * RCAP; count = min(gcur_r[b], RCAP); colbase = cb_r[b];
        dstbase = b << 10; ndst = min(1024, NREPO - dstbase); col = col_r; pos = pos_r;
    } else {
        int c = b - RB;
        rec = rec_u + (size_t)c * UCAP; count = min(gcur_u[c], UCAP); colbase = cb_u[c];
        dstbase = c << 10; ndst = min(1024, NUSER - dstbase); col = col_u; pos = pos_u;
    }
    int t = threadIdx.x;
    for (int i = t; i < 1024; i += 256) cnt[i] = 0;
    __syncthreads();
    for (int i = t; i < count; i += 256) atomicAdd(&cnt[rec[i] & 1023], 1);
    __syncthreads();
    int c0 = cnt[t * 4], c1 = cnt[t * 4 + 1], c2 = cnt[t * 4 + 2], c3 = cnt[t * 4 + 3];
    int tsum = c0 + c1 + c2 + c3;
    sc0[t] = tsum; __syncthreads();
    int* src = sc0; int* dst = sc1;
    for (int off = 1; off < 256; off <<= 1) {
        int x = src[t]; if (t >= off) x += src[t - off];
        dst[t] = x; __syncthreads();
        int* tmp = src; src = dst; dst = tmp;
    }
    int exclT = src[t] - tsum;
    int e0 = exclT, e1 = e0 + c0, e2 = e1 + c1, e3 = e2 + c2;
    excl[t * 4] = e0; excl[t * 4 + 1] = e1; excl[t * 4 + 2] = e2; excl[t * 4 + 3] = e3;
    // pos = inclusive ends in global col coords (sequential writes)
    {
        int i = t * 4;
        if (i < ndst)     pos[dstbase + i]     = colbase + e1;
        if (i + 1 < ndst) pos[dstbase + i + 1] = colbase + e2;
        if (i + 2 < ndst) pos[dstbase + i + 2] = colbase + e3;
        if (i + 3 < ndst) pos[dstbase + i + 3] = colbase + e3 + c3;
    }
    __syncthreads();
    for (int i = t; i < 1024; i += 256) cnt[i] = 0;
    __syncthreads();
    for (int i = t; i < count; i += 256) {
        u32 rc = rec[i];
        int dl = rc & 1023;
        int rk = atomicAdd(&cnt[dl], 1);
        col[colbase + excl[dl] + rk] = (int)(rc >> 10);
    }
}

// One wave per destination: mean of bf16 source rows (fp32 accum), write bf16.
// pos[] holds bucket ENDS; start = pos[d-1] (or 0).
__global__ void gather_mean_kernel(const u16* __restrict__ feat, const int* __restrict__ col,
                                   const int* __restrict__ pos, u16* __restrict__ outm, int ndst) {
    int gw = (blockIdx.x * blockDim.x + threadIdx.x) >> 6;
    int lane = threadIdx.x & 63;
    if (gw >= ndst) return;
    int start = (gw == 0) ? 0 : pos[gw - 1];
    int end = pos[gw];
    float ax = 0.f, ay = 0.f;
    int e = start;
    for (; e + 3 < end; e += 4) {
        int s0 = col[e], s1 = col[e + 1], s2 = col[e + 2], s3 = col[e + 3];
        u32 w0 = *(const u32*)(feat + (size_t)s0 * 128 + lane * 2);
        u32 w1 = *(const u32*)(feat + (size_t)s1 * 128 + lane * 2);
        u32 w2 = *(const u32*)(feat + (size_t)s2 * 128 + lane * 2);
        u32 w3 = *(const u32*)(feat + (size_t)s3 * 128 + lane * 2);
        ax += bflo(w0) + bflo(w1) + bflo(w2) + bflo(w3);
        ay += bfhi(w0) + bfhi(w1) + bfhi(w2) + bfhi(w3);
    }
    for (; e < end; ++e) {
        int s0 = col[e];
        u32 w0 = *(const u32*)(feat + (size_t)s0 * 128 + lane * 2);
        ax += bflo(w0); ay += bfhi(w0);
    }
    float inv = 1.0f / fmaxf((float)(end - start), 1.0f);
    u32 o = (u32)f2bf(ax * inv) | ((u32)f2bf(ay * inv) << 16);
    *(u32*)(outm + (size_t)gw * 128 + lane * 2) = o;
}

// MFMA transform: out[N x 128] = [mean|x] @ [Wl;Wr] + bias (opt relu).
__global__ __launch_bounds__(256)
void transform_mfma(const u16* __restrict__ A, const u16* __restrict__ X,
                    const u16* __restrict__ Wt, const float* __restrict__ bias,
                    u16* __restrict__ out_bf, float* __restrict__ out_f32,
                    int N, int do_relu) {
    __shared__ __align__(16) u16 sA[64][264];
    int tid = threadIdx.x;
    int w = tid >> 6, lane = tid & 63;
    int q = lane >> 4, n = lane & 15;
    int nb = w * 32;

    bf16x8 bfrag[2][8];
#pragma unroll
    for (int nt = 0; nt < 2; ++nt)
#pragma unroll
        for (int ks = 0; ks < 8; ++ks)
            bfrag[nt][ks] = as_bf16x8(*(const uint4*)(Wt + (size_t)(nb + nt * 16 + n) * 256 + ks * 32 + q * 8));
    float bv[2] = { bias[nb + n], bias[nb + 16 + n] };

    int base = blockIdx.x * 64;
    {
        int r = tid >> 2, c = tid & 3;
        int node = base + r;
        uint4 z = make_uint4(0, 0, 0, 0);
        uint4 va[4], vx[4];
        if (node < N) {
            const uint4* pa = (const uint4*)(A + (size_t)node * 128 + c * 32);
            const uint4* px = (const uint4*)(X + (size_t)node * 128 + c * 32);
#pragma unroll
            for (int j = 0; j < 4; ++j) { va[j] = pa[j]; vx[j] = px[j]; }
        } else {
#pragma unroll
            for (int j = 0; j < 4; ++j) { va[j] = z; vx[j] = z; }
        }
#pragma unroll
        for (int j = 0; j < 4; ++j) {
            *(uint4*)&sA[r][c * 32 + j * 8] = va[j];
            *(uint4*)&sA[r][128 + c * 32 + j * 8] = vx[j];
        }
    }
    __syncthreads();

    f32x4 zz = { 0.f, 0.f, 0.f, 0.f };
    f32x4 acc[4][2];
#pragma unroll
    for (int mt = 0; mt < 4; ++mt) { acc[mt][0] = zz; acc[mt][1] = zz; }

#pragma unroll
    for (int ks = 0; ks < 8; ++ks)
#pragma unroll
        for (int mt = 0; mt < 4; ++mt) {
            bf16x8 af = *(const bf16x8*)&sA[mt * 16 + n][ks * 32 + q * 8];
            acc[mt][0] = __builtin_amdgcn_mfma_f32_16x16x32_bf16(af, bfrag[0][ks], acc[mt][0], 0, 0, 0);
            acc[mt][1] = __builtin_amdgcn_mfma_f32_16x16x32_bf16(af, bfrag[1][ks], acc[mt][1], 0, 0, 0);
        }

#pragma unroll
    for (int mt = 0; mt < 4; ++mt) {
        int row0 = base + mt * 16 + q * 4;
#pragma unroll
        for (int nt = 0; nt < 2; ++nt) {
            int colg = nb + nt * 16 + n;
#pragma unroll
            for (int r = 0; r < 4; ++r) {
                int row = row0 + r;
                if (row < N) {
                    float v = acc[mt][nt][r] + bv[nt];
                    if (do_relu) v = fmaxf(v, 0.f);
                    if (out_bf) out_bf[(size_t)row * 128 + colg] = f2bf(v);
                    else        out_f32[(size_t)row * 128 + colg] = v;
                }
            }
        }
    }
}

extern "C" void kernel_launch(void* const* d_in, const int* in_sizes, int n_in,
                              void* d_out, int out_size, void* d_ws, size_t ws_size,
                              hipStream_t stream) {
    const float* x_user = (const float*)d_in[0];
    const float* x_repo = (const float*)d_in[1];
    const u32* edges = (const u32*)d_in[2];
    const float* Wl1s = (const float*)d_in[3], *bl1s = (const float*)d_in[4], *Wr1s = (const float*)d_in[5];
    const float* Wl1r = (const float*)d_in[6], *bl1r = (const float*)d_in[7], *Wr1r = (const float*)d_in[8];
    const float* Wl2s = (const float*)d_in[9], *bl2s = (const float*)d_in[10], *Wr2s = (const float*)d_in[11];
    const float* Wl2r = (const float*)d_in[12], *bl2r = (const float*)d_in[13], *Wr2r = (const float*)d_in[14];

    float* out_user = (float*)d_out;
    float* out_repo = (float*)d_out + (size_t)NUSER * 128;

    if (ws_size < WS_NEEDED) {
        hipLaunchKernelGGL(sentinel_kernel, dim3(1), dim3(256), 0, stream, out_user);
        return;
    }

    char* ws = (char*)d_ws;
    u32* rec_r = (u32*)(ws + OFF_RECR);
    u32* rec_u = (u32*)(ws + OFF_RECU);
    u16* B0 = (u16*)(ws + OFF_B0);
    u16* B1 = (u16*)(ws + OFF_B1);
    u16* B2 = (u16*)(ws + OFF_B2);
    u16* B3 = (u16*)(ws + OFF_B3);
    int* col_r = (int*)(ws + OFF_COLR);
    int* col_u = (int*)(ws + OFF_COLU);
    int* pos_r = (int*)(ws + OFF_POSR);
    int* pos_u = (int*)(ws + OFF_POSU);
    u16* wt1s = (u16*)(ws + OFF_WT);
    u16* wt1r = wt1s + 32768;
    u16* wt2s = wt1r + 32768;
    u16* wt2r = wt2s + 32768;
    int* gcur_r = (int*)(ws + OFF_CUR);          // 400 B
    int* gcur_u = (int*)(ws + OFF_CUR + 400);    // 800 B
    int* cb_r   = (int*)(ws + OFF_CUR + 1200);   // 400 B
    int* cb_u   = (int*)(ws + OFF_CUR + 1600);   // 800 B

    // CSR build (binned, L2-confined scatter)
    hipLaunchKernelGGL(zero_i32_kernel, dim3(1), dim3(256), 0, stream, (int4*)gcur_r, 300 / 4);
    hipLaunchKernelGGL(passA_bin, dim3(367), dim3(256), 0, stream, edges, rec_r, rec_u, gcur_r, gcur_u);
    hipLaunchKernelGGL(bucket_scan, dim3(1), dim3(256), 0, stream, gcur_r, gcur_u, cb_r, cb_u);
    hipLaunchKernelGGL(passB_build, dim3(RB + UB), dim3(256), 0, stream,
                       rec_r, rec_u, gcur_r, gcur_u, cb_r, cb_u, col_r, col_u, pos_r, pos_u);

    // weight prep + input converts (records dead from here; B-regions live)
    hipLaunchKernelGGL(wprep_kernel, dim3(128), dim3(256), 0, stream, Wl1s, Wr1s, wt1s);
    hipLaunchKernelGGL(wprep_kernel, dim3(128), dim3(256), 0, stream, Wl1r, Wr1r, wt1r);
    hipLaunchKernelGGL(wprep_kernel, dim3(128), dim3(256), 0, stream, Wl2s, Wr2s, wt2s);
    hipLaunchKernelGGL(wprep_kernel, dim3(128), dim3(256), 0, stream, Wl2r, Wr2r, wt2r);
    hipLaunchKernelGGL(cvt_bf16_kernel, dim3(25000), dim3(256), 0, stream,
                       (const float4*)x_user, (uint2*)B2, NUSER * 128 / 4);
    hipLaunchKernelGGL(cvt_bf16_kernel, dim3(12500), dim3(256), 0, stream,
                       (const float4*)x_repo, (uint2*)B3, NREPO * 128 / 4);

    // Layer 1: gathers then transforms (in-place mean -> hidden, relu)
    hipLaunchKernelGGL(gather_mean_kernel, dim3(25000), dim3(256), 0, stream, B2, col_r, pos_r, B1, NREPO);
    hipLaunchKernelGGL(gather_mean_kernel, dim3(50000), dim3(256), 0, stream, B3, col_u, pos_u, B0, NUSER);
    hipLaunchKernelGGL(transform_mfma, dim3((NREPO + 63) / 64), dim3(256), 0, stream,
                       B1, B3, wt1s, bl1s, B1, (float*)nullptr, NREPO, 1);
    hipLaunchKernelGGL(transform_mfma, dim3((NUSER + 63) / 64), dim3(256), 0, stream,
                       B0, B2, wt1r, bl1r, B0, (float*)nullptr, NUSER, 1);

    // Layer 2: gathers over hiddens, transforms write fp32 d_out
    hipLaunchKernelGGL(gather_mean_kernel, dim3(25000), dim3(256), 0, stream, B0, col_r, pos_r, B3, NREPO);
    hipLaunchKernelGGL(gather_mean_kernel, dim3(50000), dim3(256), 0, stream, B1, col_u, pos_u, B2, NUSER);
    hipLaunchKernelGGL(transform_mfma, dim3((NREPO + 63) / 64), dim3(256), 0, stream,
                       B3, B1, wt2s, bl2s, (u16*)nullptr, out_repo, NREPO, 0);
    hipLaunchKernelGGL(transform_mfma, dim3((NUSER + 63) / 64), dim3(256), 0, stream,
                       B2, B0, wt2r, bl2r, (u16*)nullptr, out_user, NUSER, 0);
}